// Round 13
// baseline (263.059 us; speedup 1.0000x reference)
//
#include <hip/hip_runtime.h>
#include <hip/hip_fp16.h>

#define N_NODES 50000
#define N_EDGES 800000
#define NEG_SLOPE 0.2f
#define LN_EPS 1e-5f
#define ALPHA_BLOCKS 1024
#define H1_BLOCKS 3125     // N_EDGES / 256 exactly
#define NB1 391            // ceil(50000/128) coarse buckets (dst>>7)
#define NB1P 392           // padded

typedef _Float16 f16;
typedef f16 f16x4 __attribute__((ext_vector_type(4)));
typedef f16 f16x8 __attribute__((ext_vector_type(8)));
typedef float f32x4 __attribute__((ext_vector_type(4)));

// ---------------- k_pre: tiny precomputes (unchanged) ----------------
__global__ __launch_bounds__(256) void k_pre(
    const float* __restrict__ Wn, const float* __restrict__ bn,
    const float* __restrict__ att, const float* __restrict__ Ws,
    const float* __restrict__ bias,
    float* __restrict__ qu, float* __restrict__ qv, float* __restrict__ cuv,
    f16* __restrict__ Mt16, float* __restrict__ cvec)
{
    const int b = blockIdx.x, t = threadIdx.x;
    if (b < 64) {
        int e = b * 256 + t;
        int hd = e >> 12, k = (e >> 6) & 63, c = e & 63;
        float s = 0.f;
        for (int j = 0; j < 64; ++j)
            s = fmaf(Wn[k * 256 + hd * 64 + j], Ws[(hd * 64 + j) * 64 + c], s);
        Mt16[c * 256 + hd * 64 + k] = (f16)s;
    } else if (b == 64) {
        int hd = t >> 6, k = t & 63;
        float su = 0.f, sv = 0.f;
        for (int j = 0; j < 64; ++j) {
            float w = Wn[k * 256 + hd * 64 + j];
            su = fmaf(w, att[hd * 128 + j], su);
            sv = fmaf(w, att[hd * 128 + 64 + j], sv);
        }
        qu[hd * 64 + k] = su;
        qv[hd * 64 + k] = sv;
        if (t < 8) {
            int hh = t & 3;
            const float* a = att + hh * 128 + (t >> 2) * 64;
            float s = 0.f;
            for (int j = 0; j < 64; ++j) s = fmaf(bn[hh * 64 + j], a[j], s);
            cuv[t] = s;
        }
    } else {
        if (t < 64) {
            float s = bias[t];
            for (int kk = 0; kk < 256; ++kk) s = fmaf(bn[kk], Ws[kk * 64 + t], s);
            cvec[t] = s;
        }
    }
}

// ---------------- k_front3: [0,1024) alphas + h16; [1024,1024+3125) LDS coarse histogram ----------
__global__ __launch_bounds__(256) void k_front3(
    const float* __restrict__ h, const int* __restrict__ dst,
    const float* __restrict__ qu, const float* __restrict__ qv, const float* __restrict__ cuv,
    __half* __restrict__ h16, float* __restrict__ alpha_u, float* __restrict__ alpha_v,
    int* __restrict__ g)
{
    __shared__ int hist[NB1P];
    const int t = threadIdx.x;
    if (blockIdx.x >= ALPHA_BLOCKS) {
        const int blk = blockIdx.x - ALPHA_BLOCKS;
        for (int i = t; i < NB1P; i += 256) hist[i] = 0;   // FIX: strided (NB1P > 256)
        __syncthreads();
        const int e = blk * 256 + t;            // < 800000 exactly
        atomicAdd(&hist[dst[e] >> 7], 1);       // LDS atomic
        __syncthreads();
        for (int i = t; i < NB1P; i += 256) g[blk * NB1P + i] = hist[i];  // FIX: strided
        return;
    }
    const int lane = t & 63;
    const int wid = blockIdx.x * 4 + (t >> 6);
    const float qur0 = qu[lane], qur1 = qu[64 + lane], qur2 = qu[128 + lane], qur3 = qu[192 + lane];
    const float qvr0 = qv[lane], qvr1 = qv[64 + lane], qvr2 = qv[128 + lane], qvr3 = qv[192 + lane];
    const float4 cu = *(const float4*)cuv;
    const float4 cv = *(const float4*)(cuv + 4);
    for (int n = wid; n < N_NODES; n += ALPHA_BLOCKS * 4) {
        float hv = h[(size_t)n * 64 + lane];
        h16[(size_t)n * 64 + lane] = __float2half(hv);
        float pu0 = hv * qur0, pu1 = hv * qur1, pu2 = hv * qur2, pu3 = hv * qur3;
        float pv0 = hv * qvr0, pv1 = hv * qvr1, pv2 = hv * qvr2, pv3 = hv * qvr3;
#pragma unroll
        for (int off = 32; off; off >>= 1) {
            pu0 += __shfl_xor(pu0, off);
            pu1 += __shfl_xor(pu1, off);
            pu2 += __shfl_xor(pu2, off);
            pu3 += __shfl_xor(pu3, off);
            pv0 += __shfl_xor(pv0, off);
            pv1 += __shfl_xor(pv1, off);
            pv2 += __shfl_xor(pv2, off);
            pv3 += __shfl_xor(pv3, off);
        }
        if (lane == 0) {
            *(float4*)(alpha_u + n * 4) = make_float4(pu0 + cu.x, pu1 + cu.y, pu2 + cu.z, pu3 + cu.w);
            *(float4*)(alpha_v + n * 4) = make_float4(pv0 + cv.x, pv1 + cv.y, pv2 + cv.z, pv3 + cv.w);
        }
    }
}

__device__ __forceinline__ int wave_incl_scan(int x, int lane) {
#pragma unroll
    for (int off = 1; off < 64; off <<= 1) {
        int y = __shfl_up(x, off);
        if (lane >= off) x += y;
    }
    return x;
}

// ---------------- k_s1: per coarse bucket, exclusive prefix over the 3125 block counts ----------
__global__ __launch_bounds__(64) void k_s1(const int* __restrict__ g,
                                           int* __restrict__ off1, int* __restrict__ tot) {
    const int b = blockIdx.x;       // [0, NB1)
    const int lane = threadIdx.x;
    int running = 0;
    for (int c = 0; c < H1_BLOCKS; c += 64) {
        const int blk = c + lane;
        int v = (blk < H1_BLOCKS) ? g[blk * NB1P + b] : 0;
        int incl = wave_incl_scan(v, lane);
        if (blk < H1_BLOCKS) off1[blk * NB1P + b] = running + incl - v;
        running += __shfl(incl, 63);
    }
    if (lane == 0) tot[b] = running;
}

// ---------------- k_base: single-wave scan of bucket totals -> base offsets ----------------
__global__ __launch_bounds__(64) void k_base(const int* __restrict__ tot, int* __restrict__ base) {
    const int lane = threadIdx.x;
    int running = 0;
    for (int c = 0; c < NB1P; c += 64) {
        const int i = c + lane;
        int v = (i < NB1) ? tot[i] : 0;
        int incl = wave_incl_scan(v, lane);
        if (i < NB1P) base[i] = running + incl - v;   // base[NB1] = E
        running += __shfl(incl, 63);
    }
}

// ---------------- k_h1scat: scatter packed edges into bucket-contiguous ebuf ----------------
__global__ __launch_bounds__(256) void k_h1scat(
    const int* __restrict__ src, const int* __restrict__ dst,
    const int* __restrict__ base, const int* __restrict__ off1,
    int* __restrict__ ebuf)
{
    __shared__ int cur[NB1P];
    const int t = threadIdx.x;
    const int blk = blockIdx.x;
    for (int i = t; i < NB1P; i += 256)                // FIX: strided (NB1P > 256)
        cur[i] = (i < NB1) ? base[i] + off1[blk * NB1P + i] : 0;
    __syncthreads();
    const int e = blk * 256 + t;
    const int s = src[e], d = dst[e];
    const int pos = atomicAdd(&cur[d >> 7], 1);     // LDS atomic
    ebuf[pos] = (s << 7) | (d & 127);
}

// ---------------- k_h2: per bucket fine sort; writes rowptr, csr_src, csr_w ----------------
__global__ __launch_bounds__(256) void k_h2(
    const int* __restrict__ ebuf, const int* __restrict__ base,
    const float* __restrict__ alpha_u, const float* __restrict__ alpha_v,
    int* __restrict__ rowptr, int* __restrict__ csr_src, float* __restrict__ csr_w)
{
    __shared__ int hist[128], lscan[128], cur[128];
    const int t = threadIdx.x;
    const int b = blockIdx.x;
    const int r0 = base[b], r1 = base[b + 1];
    if (t < 128) hist[t] = 0;
    __syncthreads();
    for (int j = r0 + t; j < r1; j += 256) atomicAdd(&hist[ebuf[j] & 127], 1);
    __syncthreads();
    if (t < 64) {
        int running = 0;
        for (int c = 0; c < 128; c += 64) {
            int v = hist[c + t];
            int incl = wave_incl_scan(v, t);
            lscan[c + t] = running + incl - v;
            running += __shfl(incl, 63);
        }
    }
    __syncthreads();
    if (t < 128) {
        const int n = b * 128 + t;
        if (n <= N_NODES) rowptr[n] = r0 + lscan[t];
        cur[t] = lscan[t];
    }
    __syncthreads();
    for (int j = r0 + t; j < r1; j += 256) {
        const int p = ebuf[j];
        const int dl = p & 127, s = p >> 7;
        const int pos = r0 + atomicAdd(&cur[dl], 1);   // LDS atomic
        const int d = b * 128 + dl;
        const float4 au = *(const float4*)(alpha_u + (size_t)s * 4);
        const float4 av = *(const float4*)(alpha_v + (size_t)d * 4);
        float l0 = au.x + av.x; l0 = l0 > 0.f ? l0 : NEG_SLOPE * l0;
        float l1 = au.y + av.y; l1 = l1 > 0.f ? l1 : NEG_SLOPE * l1;
        float l2 = au.z + av.z; l2 = l2 > 0.f ? l2 : NEG_SLOPE * l2;
        float l3 = au.w + av.w; l3 = l3 > 0.f ? l3 : NEG_SLOPE * l3;
        csr_src[pos] = s;
        *(float4*)(csr_w + (size_t)pos * 4) =
            make_float4(__expf(l0), __expf(l1), __expf(l2), __expf(l3));
    }
}

// ---------------- k_agg3: one wave per node; precomputed weights; gather h16[src] ----------------
__global__ __launch_bounds__(256) void k_agg3(
    const int* __restrict__ rowptr, const int* __restrict__ csr_src,
    const float* __restrict__ csr_w, const __half* __restrict__ h16,
    f16* __restrict__ aggh16, int n0, int n1)
{
    const int lane = threadIdx.x & 63;
    const int wid = (blockIdx.x * 256 + threadIdx.x) >> 6;
    const int nwaves = (gridDim.x * 256) >> 6;
    for (int n = n0 + wid; n < n1; n += nwaves) {
        const int r0 = rowptr[n], r1 = rowptr[n + 1];
        float d0 = 0.f, d1 = 0.f, d2 = 0.f, d3 = 0.f;
        float a0 = 0.f, a1 = 0.f, a2 = 0.f, a3 = 0.f;
        const int rlast = r1 - 1;
        for (int j = r0; j < r1; j += 8) {
            int jdx[8], s[8];
#pragma unroll
            for (int i = 0; i < 8; ++i) {
                int jj = j + i;
                jdx[i] = jj < rlast ? jj : rlast;
                s[i] = __builtin_amdgcn_readfirstlane(csr_src[jdx[i]]);
            }
            float hv[8];
#pragma unroll
            for (int i = 0; i < 8; ++i)
                hv[i] = __half2float(h16[(size_t)s[i] * 64 + lane]);
            float4 w[8];
#pragma unroll
            for (int i = 0; i < 8; ++i)
                w[i] = *(const float4*)(csr_w + (size_t)jdx[i] * 4);
#pragma unroll
            for (int i = 0; i < 8; ++i) {
                const bool valid = (j + i < r1);
                float e0 = valid ? w[i].x : 0.f;
                float e1 = valid ? w[i].y : 0.f;
                float e2 = valid ? w[i].z : 0.f;
                float e3 = valid ? w[i].w : 0.f;
                d0 += e0; a0 = fmaf(e0, hv[i], a0);
                d1 += e1; a1 = fmaf(e1, hv[i], a1);
                d2 += e2; a2 = fmaf(e2, hv[i], a2);
                d3 += e3; a3 = fmaf(e3, hv[i], a3);
            }
        }
        const float i0 = 1.0f / fmaxf(d0, 1e-16f);
        const float i1 = 1.0f / fmaxf(d1, 1e-16f);
        const float i2 = 1.0f / fmaxf(d2, 1e-16f);
        const float i3 = 1.0f / fmaxf(d3, 1e-16f);
        f16* __restrict__ arow = aggh16 + (size_t)n * 256;
        arow[lane]       = (f16)(a0 * i0);
        arow[64 + lane]  = (f16)(a1 * i1);
        arow[128 + lane] = (f16)(a2 * i2);
        arow[192 + lane] = (f16)(a3 * i3);
    }
}

// ---------------- k_post_mfma (unchanged) ----------------
__global__ __launch_bounds__(256) void k_post_mfma(
    const f16* __restrict__ aggh16, const f16* __restrict__ Mt16,
    const float* __restrict__ cvec, const float* __restrict__ h,
    const float* __restrict__ gamma_, const float* __restrict__ beta_,
    float* __restrict__ out)
{
    __shared__ f16 Mlds[64 * 256];
    const int t = threadIdx.x;
    {
        const uint4* g = (const uint4*)Mt16;
        uint4* l = (uint4*)Mlds;
#pragma unroll
        for (int i = 0; i < 8; ++i) {
            int ch = i * 256 + t;
            l[ch ^ ((ch >> 5) & 7)] = g[ch];
        }
    }
    __syncthreads();
    const int lane = t & 63;
    const int l15 = lane & 15, lg = lane >> 4;
    float cv_r[4], ga_r[4], be_r[4];
#pragma unroll
    for (int ct = 0; ct < 4; ++ct) {
        int c = ct * 16 + l15;
        cv_r[ct] = cvec[c]; ga_r[ct] = gamma_[c]; be_r[ct] = beta_[c];
    }
    const int wid0 = (blockIdx.x * 256 + t) >> 6;
    const int nw = (gridDim.x * 256) >> 6;
    for (int blk = wid0; blk < N_NODES / 16; blk += nw) {
        f32x4 acc[4] = {{0.f,0.f,0.f,0.f},{0.f,0.f,0.f,0.f},{0.f,0.f,0.f,0.f},{0.f,0.f,0.f,0.f}};
        const f16* arow = aggh16 + (size_t)(blk * 16 + l15) * 256 + 4 * lg;
#pragma unroll
        for (int ks = 0; ks < 8; ++ks) {
            f16x4 alo = *(const f16x4*)(arow + ks * 32);
            f16x4 ahi = *(const f16x4*)(arow + ks * 32 + 16);
            f16x8 a;
            a[0]=alo[0]; a[1]=alo[1]; a[2]=alo[2]; a[3]=alo[3];
            a[4]=ahi[0]; a[5]=ahi[1]; a[6]=ahi[2]; a[7]=ahi[3];
#pragma unroll
            for (int ct = 0; ct < 4; ++ct) {
                const int c = ct * 16 + l15;
                const int sw = (c & 7) << 3;
                const int u0 = (c * 256 + ks * 32 + 4 * lg);
                f16x4 blo = *(const f16x4*)(Mlds + (u0 ^ sw));
                f16x4 bhi = *(const f16x4*)(Mlds + ((u0 + 16) ^ sw));
                f16x8 b;
                b[0]=blo[0]; b[1]=blo[1]; b[2]=blo[2]; b[3]=blo[3];
                b[4]=bhi[0]; b[5]=bhi[1]; b[6]=bhi[2]; b[7]=bhi[3];
                acc[ct] = __builtin_amdgcn_mfma_f32_16x16x32_f16(a, b, acc[ct], 0, 0, 0);
            }
        }
#pragma unroll
        for (int e = 0; e < 4; ++e) {
            const int gr = blk * 16 + 4 * lg + e;
            float x[4];
            float s = 0.f;
#pragma unroll
            for (int ct = 0; ct < 4; ++ct) {
                x[ct] = acc[ct][e] + cv_r[ct] + h[(size_t)gr * 64 + ct * 16 + l15];
                s += x[ct];
            }
            s += __shfl_xor(s, 1); s += __shfl_xor(s, 2);
            s += __shfl_xor(s, 4); s += __shfl_xor(s, 8);
            const float mu = s * (1.0f / 64.0f);
            float v = 0.f;
#pragma unroll
            for (int ct = 0; ct < 4; ++ct) { float d = x[ct] - mu; v = fmaf(d, d, v); }
            v += __shfl_xor(v, 1); v += __shfl_xor(v, 2);
            v += __shfl_xor(v, 4); v += __shfl_xor(v, 8);
            const float rinv = rsqrtf(v * (1.0f / 64.0f) + LN_EPS);
#pragma unroll
            for (int ct = 0; ct < 4; ++ct) {
                float xn = (x[ct] - mu) * rinv;
                out[(size_t)gr * 64 + ct * 16 + l15] = fmaxf(xn * ga_r[ct] + be_r[ct], 0.0f);
            }
        }
    }
}

extern "C" void kernel_launch(void* const* d_in, const int* in_sizes, int n_in,
                              void* d_out, int out_size, void* d_ws, size_t ws_size,
                              hipStream_t stream) {
    const float* h      = (const float*)d_in[0];
    const int*   src    = (const int*)d_in[1];
    const int*   dst    = (const int*)d_in[2];
    const float* Wn     = (const float*)d_in[3];
    const float* bn     = (const float*)d_in[4];
    const float* att    = (const float*)d_in[5];
    const float* Ws     = (const float*)d_in[6];
    const float* bias   = (const float*)d_in[7];
    const float* gamma_ = (const float*)d_in[8];
    const float* beta_  = (const float*)d_in[9];
    float* out = (float*)d_out;

    char* ws = (char*)d_ws;
    size_t off = 0;
    auto alloc = [&](size_t bytes) { void* p = ws + off; off = (off + bytes + 255) & ~(size_t)255; return p; };
    __half* h16    = (__half*)alloc((size_t)N_NODES * 64 * 2);      // 6.4 MB
    f16*   aggh16  = (f16*)alloc((size_t)N_NODES * 256 * 2);        // 25.6 MB
    float* alpha_u = (float*)alloc((size_t)N_NODES * 4 * 4);
    float* alpha_v = (float*)alloc((size_t)N_NODES * 4 * 4);
    int*   rowptr  = (int*)alloc((size_t)(N_NODES + 1) * 4);
    int*   csr_src = (int*)alloc((size_t)N_EDGES * 4);              // 3.2 MB
    float* csr_w   = (float*)alloc((size_t)N_EDGES * 4 * 4);        // 12.8 MB
    int*   g       = (int*)alloc((size_t)H1_BLOCKS * NB1P * 4);     // 4.9 MB
    int*   off1    = (int*)alloc((size_t)H1_BLOCKS * NB1P * 4);     // 4.9 MB
    int*   tot     = (int*)alloc((size_t)NB1P * 4);
    int*   base    = (int*)alloc((size_t)(NB1P + 1) * 4);
    int*   ebuf    = (int*)alloc((size_t)N_EDGES * 4);              // 3.2 MB
    float* qu      = (float*)alloc(256 * 4);
    float* qv      = (float*)alloc(256 * 4);
    float* cuv     = (float*)alloc(8 * 4);
    f16*   Mt16    = (f16*)alloc(16384 * 2);                        // 32 KB
    float* cvec    = (float*)alloc(64 * 4);

    k_pre<<<66, 256, 0, stream>>>(Wn, bn, att, Ws, bias, qu, qv, cuv, Mt16, cvec);
    k_front3<<<ALPHA_BLOCKS + H1_BLOCKS, 256, 0, stream>>>(h, dst, qu, qv, cuv,
                                                           h16, alpha_u, alpha_v, g);
    k_s1<<<NB1, 64, 0, stream>>>(g, off1, tot);
    k_base<<<1, 64, 0, stream>>>(tot, base);
    k_h1scat<<<H1_BLOCKS, 256, 0, stream>>>(src, dst, base, off1, ebuf);
    k_h2<<<NB1, 256, 0, stream>>>(ebuf, base, alpha_u, alpha_v, rowptr, csr_src, csr_w);
    k_agg3<<<2048, 256, 0, stream>>>(rowptr, csr_src, csr_w, h16, aggh16, 0, 12500);
    k_agg3<<<2048, 256, 0, stream>>>(rowptr, csr_src, csr_w, h16, aggh16, 12500, 25000);
    k_agg3<<<2048, 256, 0, stream>>>(rowptr, csr_src, csr_w, h16, aggh16, 25000, 37500);
    k_agg3<<<2048, 256, 0, stream>>>(rowptr, csr_src, csr_w, h16, aggh16, 37500, N_NODES);
    k_post_mfma<<<782, 256, 0, stream>>>(aggh16, Mt16, cvec, h, gamma_, beta_, out);
}

// Round 14
// 236.873 us; speedup vs baseline: 1.1106x; 1.1106x over previous
//
#include <hip/hip_runtime.h>
#include <hip/hip_fp16.h>

#define N_NODES 50000
#define N_EDGES 800000
#define NEG_SLOPE 0.2f
#define LN_EPS 1e-5f
#define ALPHA_BLOCKS 1024
#define PRE_BLOCKS 65      // 64 Mt16 + 1 cvec
#define EPB 512            // edges per histogram/scatter block
#define HB 1563            // ceil(N_EDGES/EPB)
#define NB1 391            // ceil(50000/128) coarse buckets (dst>>7)
#define NB1P 392

typedef _Float16 f16;
typedef f16 f16x4 __attribute__((ext_vector_type(4)));
typedef f16 f16x8 __attribute__((ext_vector_type(8)));
typedef float f32x4 __attribute__((ext_vector_type(4)));

__device__ __forceinline__ int wave_incl_scan(int x, int lane) {
#pragma unroll
    for (int off = 1; off < 64; off <<= 1) {
        int y = __shfl_up(x, off);
        if (lane >= off) x += y;
    }
    return x;
}

// ---------------- L1 mega: [0,64) Mt16 | [64] cvec | [65,65+1024) alphas+h16 | rest: histogram ----
__global__ __launch_bounds__(256) void k_mega1(
    const float* __restrict__ h, const float* __restrict__ Wn,
    const float* __restrict__ bn, const float* __restrict__ att,
    const float* __restrict__ Ws, const float* __restrict__ bias,
    const int* __restrict__ dst,
    __half* __restrict__ h16, float* __restrict__ alpha_u, float* __restrict__ alpha_v,
    f16* __restrict__ Mt16, float* __restrict__ cvec, int* __restrict__ g)
{
    __shared__ float squ[256], sqv[256], scuv[8];
    __shared__ int shist[NB1P];
    const int b = blockIdx.x, t = threadIdx.x;

    if (b < 64) {                       // Mt16[c][hd*64+k] = (Wn_hd @ Ws_hd)^T, fp16
        int e = b * 256 + t;
        int hd = e >> 12, k = (e >> 6) & 63, c = e & 63;
        float s = 0.f;
        for (int j = 0; j < 64; ++j)
            s = fmaf(Wn[k * 256 + hd * 64 + j], Ws[(hd * 64 + j) * 64 + c], s);
        Mt16[c * 256 + hd * 64 + k] = (f16)s;
        return;
    }
    if (b == 64) {                      // cvec = bias + bn @ Ws
        if (t < 64) {
            float s = bias[t];
            for (int kk = 0; kk < 256; ++kk) s = fmaf(bn[kk], Ws[kk * 64 + t], s);
            cvec[t] = s;
        }
        return;
    }
    if (b >= PRE_BLOCKS + ALPHA_BLOCKS) {   // coarse histogram, 512 edges/block
        const int blk = b - (PRE_BLOCKS + ALPHA_BLOCKS);
        for (int i = t; i < NB1P; i += 256) shist[i] = 0;
        __syncthreads();
        const int e0 = blk * EPB;
        const int e1 = (e0 + EPB < N_EDGES) ? e0 + EPB : N_EDGES;
        for (int e = e0 + t; e < e1; e += 256) atomicAdd(&shist[dst[e] >> 7], 1);
        __syncthreads();
        for (int i = t; i < NB1P; i += 256) g[blk * NB1P + i] = shist[i];
        return;
    }
    // ---- alphas + h16 cast; qu/qv/cuv computed locally in LDS ----
    {
        const int hd = t >> 6, k = t & 63;
        const float* wrow = Wn + k * 256 + hd * 64;
        const float* arow = att + hd * 128;
        float su = 0.f, sv = 0.f;
        for (int j = 0; j < 64; ++j) {
            float w = wrow[j];
            su = fmaf(w, arow[j], su);
            sv = fmaf(w, arow[64 + j], sv);
        }
        squ[t] = su; sqv[t] = sv;
        if (t < 8) {
            int hh = t & 3;
            const float* a2 = att + hh * 128 + (t >> 2) * 64;
            float s = 0.f;
            for (int j = 0; j < 64; ++j) s = fmaf(bn[hh * 64 + j], a2[j], s);
            scuv[t] = s;                 // [0..3]=cu, [4..7]=cv
        }
    }
    __syncthreads();
    const int lane = t & 63;
    const int wid = (b - PRE_BLOCKS) * 4 + (t >> 6);
    const float qur0 = squ[lane], qur1 = squ[64 + lane], qur2 = squ[128 + lane], qur3 = squ[192 + lane];
    const float qvr0 = sqv[lane], qvr1 = sqv[64 + lane], qvr2 = sqv[128 + lane], qvr3 = sqv[192 + lane];
    const float4 cu = make_float4(scuv[0], scuv[1], scuv[2], scuv[3]);
    const float4 cv = make_float4(scuv[4], scuv[5], scuv[6], scuv[7]);
    for (int n = wid; n < N_NODES; n += ALPHA_BLOCKS * 4) {
        float hv = h[(size_t)n * 64 + lane];
        h16[(size_t)n * 64 + lane] = __float2half(hv);
        float pu0 = hv * qur0, pu1 = hv * qur1, pu2 = hv * qur2, pu3 = hv * qur3;
        float pv0 = hv * qvr0, pv1 = hv * qvr1, pv2 = hv * qvr2, pv3 = hv * qvr3;
#pragma unroll
        for (int off = 32; off; off >>= 1) {
            pu0 += __shfl_xor(pu0, off);
            pu1 += __shfl_xor(pu1, off);
            pu2 += __shfl_xor(pu2, off);
            pu3 += __shfl_xor(pu3, off);
            pv0 += __shfl_xor(pv0, off);
            pv1 += __shfl_xor(pv1, off);
            pv2 += __shfl_xor(pv2, off);
            pv3 += __shfl_xor(pv3, off);
        }
        if (lane == 0) {
            *(float4*)(alpha_u + n * 4) = make_float4(pu0 + cu.x, pu1 + cu.y, pu2 + cu.z, pu3 + cu.w);
            *(float4*)(alpha_v + n * 4) = make_float4(pv0 + cv.x, pv1 + cv.y, pv2 + cv.z, pv3 + cv.w);
        }
    }
}

// ---------------- k_s1: 4 buckets/block; exclusive prefix over HB block counts ----------------
__global__ __launch_bounds__(256) void k_s1(const int* __restrict__ g,
                                            int* __restrict__ off1, int* __restrict__ tot) {
    const int b = blockIdx.x * 4 + (threadIdx.x >> 6);   // [0, 392)
    const int lane = threadIdx.x & 63;
    if (b >= NB1) return;
    int running = 0;
    for (int c = 0; c < HB; c += 64) {
        const int blk = c + lane;
        int v = (blk < HB) ? g[blk * NB1P + b] : 0;
        int incl = wave_incl_scan(v, lane);
        if (blk < HB) off1[blk * NB1P + b] = running + incl - v;
        running += __shfl(incl, 63);
    }
    if (lane == 0) tot[b] = running;
}

// ---------------- k_h1scat: scatter packed edges into bucket-contiguous ebuf ----------------
// base recomputed in-block from tot (kills the k_base launch).
__global__ __launch_bounds__(256) void k_h1scat(
    const int* __restrict__ src, const int* __restrict__ dst,
    const int* __restrict__ tot, const int* __restrict__ off1,
    int* __restrict__ ebuf)
{
    __shared__ int sbase[NB1P], cur[NB1P];
    const int t = threadIdx.x;
    const int blk = blockIdx.x;
    if (t < 64) {
        int running = 0;
        for (int c = 0; c < NB1P; c += 64) {
            int i = c + t;
            int v = (i < NB1) ? tot[i] : 0;
            int incl = wave_incl_scan(v, t);
            sbase[i] = running + incl - v;
            running += __shfl(incl, 63);
        }
    }
    __syncthreads();
    for (int i = t; i < NB1P; i += 256)
        cur[i] = (i < NB1) ? sbase[i] + off1[blk * NB1P + i] : 0;
    __syncthreads();
    const int e0 = blk * EPB;
    const int e1 = (e0 + EPB < N_EDGES) ? e0 + EPB : N_EDGES;
    for (int e = e0 + t; e < e1; e += 256) {
        const int s = src[e], d = dst[e];
        const int pos = atomicAdd(&cur[d >> 7], 1);     // LDS atomic
        ebuf[pos] = (s << 7) | (d & 127);
    }
}

// ---------------- k_h2: per bucket fine sort; writes rowptr, csr_src, csr_w ----------------
__global__ __launch_bounds__(256) void k_h2(
    const int* __restrict__ ebuf, const int* __restrict__ tot,
    const float* __restrict__ alpha_u, const float* __restrict__ alpha_v,
    int* __restrict__ rowptr, int* __restrict__ csr_src, float* __restrict__ csr_w)
{
    __shared__ int sbase[NB1P + 1];
    __shared__ int hist[128], lscan[128], cur[128];
    const int t = threadIdx.x;
    const int b = blockIdx.x;
    if (t < 64) {
        int running = 0;
        for (int c = 0; c < NB1P; c += 64) {
            int i = c + t;
            int v = (i < NB1) ? tot[i] : 0;
            int incl = wave_incl_scan(v, t);
            sbase[i] = running + incl - v;
            running += __shfl(incl, 63);
        }
        if (t == 0) sbase[NB1P] = N_EDGES;
    }
    __syncthreads();
    const int r0 = sbase[b], r1 = sbase[b + 1];
    if (t < 128) hist[t] = 0;
    __syncthreads();
    for (int j = r0 + t; j < r1; j += 256) atomicAdd(&hist[ebuf[j] & 127], 1);
    __syncthreads();
    if (t < 64) {
        int running = 0;
        for (int c = 0; c < 128; c += 64) {
            int v = hist[c + t];
            int incl = wave_incl_scan(v, t);
            lscan[c + t] = running + incl - v;
            running += __shfl(incl, 63);
        }
    }
    __syncthreads();
    if (t < 128) {
        const int n = b * 128 + t;
        if (n <= N_NODES) rowptr[n] = r0 + lscan[t];
        cur[t] = lscan[t];
    }
    __syncthreads();
    for (int j = r0 + t; j < r1; j += 256) {
        const int p = ebuf[j];
        const int dl = p & 127, s = p >> 7;
        const int pos = r0 + atomicAdd(&cur[dl], 1);    // LDS atomic
        const int d = b * 128 + dl;
        const float4 au = *(const float4*)(alpha_u + (size_t)s * 4);
        const float4 av = *(const float4*)(alpha_v + (size_t)d * 4);
        float l0 = au.x + av.x; l0 = l0 > 0.f ? l0 : NEG_SLOPE * l0;
        float l1 = au.y + av.y; l1 = l1 > 0.f ? l1 : NEG_SLOPE * l1;
        float l2 = au.z + av.z; l2 = l2 > 0.f ? l2 : NEG_SLOPE * l2;
        float l3 = au.w + av.w; l3 = l3 > 0.f ? l3 : NEG_SLOPE * l3;
        csr_src[pos] = s;
        *(float4*)(csr_w + (size_t)pos * 4) =
            make_float4(__expf(l0), __expf(l1), __expf(l2), __expf(l3));
    }
}

// ---------------- k_agg: ONE dispatch; one wave/node; precomputed weights; h16 gathers ----------
__global__ __launch_bounds__(256) void k_agg(
    const int* __restrict__ rowptr, const int* __restrict__ csr_src,
    const float* __restrict__ csr_w, const __half* __restrict__ h16,
    f16* __restrict__ aggh16)
{
    const int lane = threadIdx.x & 63;
    const int wid = (blockIdx.x * 256 + threadIdx.x) >> 6;
    const int nwaves = (gridDim.x * 256) >> 6;
    for (int n = wid; n < N_NODES; n += nwaves) {
        const int r0 = rowptr[n], r1 = rowptr[n + 1];
        float d0 = 0.f, d1 = 0.f, d2 = 0.f, d3 = 0.f;
        float a0 = 0.f, a1 = 0.f, a2 = 0.f, a3 = 0.f;
        const int rlast = r1 - 1;
        for (int j = r0; j < r1; j += 8) {
            int jdx[8], s[8];
#pragma unroll
            for (int i = 0; i < 8; ++i) {
                int jj = j + i;
                jdx[i] = jj < rlast ? jj : rlast;
                s[i] = __builtin_amdgcn_readfirstlane(csr_src[jdx[i]]);
            }
            float hv[8];
#pragma unroll
            for (int i = 0; i < 8; ++i)
                hv[i] = __half2float(h16[(size_t)s[i] * 64 + lane]);
            float4 w[8];
#pragma unroll
            for (int i = 0; i < 8; ++i)
                w[i] = *(const float4*)(csr_w + (size_t)jdx[i] * 4);
#pragma unroll
            for (int i = 0; i < 8; ++i) {
                const bool valid = (j + i < r1);
                float e0 = valid ? w[i].x : 0.f;
                float e1 = valid ? w[i].y : 0.f;
                float e2 = valid ? w[i].z : 0.f;
                float e3 = valid ? w[i].w : 0.f;
                d0 += e0; a0 = fmaf(e0, hv[i], a0);
                d1 += e1; a1 = fmaf(e1, hv[i], a1);
                d2 += e2; a2 = fmaf(e2, hv[i], a2);
                d3 += e3; a3 = fmaf(e3, hv[i], a3);
            }
        }
        const float i0 = 1.0f / fmaxf(d0, 1e-16f);
        const float i1 = 1.0f / fmaxf(d1, 1e-16f);
        const float i2 = 1.0f / fmaxf(d2, 1e-16f);
        const float i3 = 1.0f / fmaxf(d3, 1e-16f);
        f16* __restrict__ arow = aggh16 + (size_t)n * 256;
        arow[lane]       = (f16)(a0 * i0);
        arow[64 + lane]  = (f16)(a1 * i1);
        arow[128 + lane] = (f16)(a2 * i2);
        arow[192 + lane] = (f16)(a3 * i3);
    }
}

// ---------------- k_post_mfma (unchanged) ----------------
__global__ __launch_bounds__(256) void k_post_mfma(
    const f16* __restrict__ aggh16, const f16* __restrict__ Mt16,
    const float* __restrict__ cvec, const float* __restrict__ h,
    const float* __restrict__ gamma_, const float* __restrict__ beta_,
    float* __restrict__ out)
{
    __shared__ f16 Mlds[64 * 256];
    const int t = threadIdx.x;
    {
        const uint4* g = (const uint4*)Mt16;
        uint4* l = (uint4*)Mlds;
#pragma unroll
        for (int i = 0; i < 8; ++i) {
            int ch = i * 256 + t;
            l[ch ^ ((ch >> 5) & 7)] = g[ch];
        }
    }
    __syncthreads();
    const int lane = t & 63;
    const int l15 = lane & 15, lg = lane >> 4;
    float cv_r[4], ga_r[4], be_r[4];
#pragma unroll
    for (int ct = 0; ct < 4; ++ct) {
        int c = ct * 16 + l15;
        cv_r[ct] = cvec[c]; ga_r[ct] = gamma_[c]; be_r[ct] = beta_[c];
    }
    const int wid0 = (blockIdx.x * 256 + t) >> 6;
    const int nw = (gridDim.x * 256) >> 6;
    for (int blk = wid0; blk < N_NODES / 16; blk += nw) {
        f32x4 acc[4] = {{0.f,0.f,0.f,0.f},{0.f,0.f,0.f,0.f},{0.f,0.f,0.f,0.f},{0.f,0.f,0.f,0.f}};
        const f16* arow = aggh16 + (size_t)(blk * 16 + l15) * 256 + 4 * lg;
#pragma unroll
        for (int ks = 0; ks < 8; ++ks) {
            f16x4 alo = *(const f16x4*)(arow + ks * 32);
            f16x4 ahi = *(const f16x4*)(arow + ks * 32 + 16);
            f16x8 a;
            a[0]=alo[0]; a[1]=alo[1]; a[2]=alo[2]; a[3]=alo[3];
            a[4]=ahi[0]; a[5]=ahi[1]; a[6]=ahi[2]; a[7]=ahi[3];
#pragma unroll
            for (int ct = 0; ct < 4; ++ct) {
                const int c = ct * 16 + l15;
                const int sw = (c & 7) << 3;
                const int u0 = (c * 256 + ks * 32 + 4 * lg);
                f16x4 blo = *(const f16x4*)(Mlds + (u0 ^ sw));
                f16x4 bhi = *(const f16x4*)(Mlds + ((u0 + 16) ^ sw));
                f16x8 b;
                b[0]=blo[0]; b[1]=blo[1]; b[2]=blo[2]; b[3]=blo[3];
                b[4]=bhi[0]; b[5]=bhi[1]; b[6]=bhi[2]; b[7]=bhi[3];
                acc[ct] = __builtin_amdgcn_mfma_f32_16x16x32_f16(a, b, acc[ct], 0, 0, 0);
            }
        }
#pragma unroll
        for (int e = 0; e < 4; ++e) {
            const int gr = blk * 16 + 4 * lg + e;
            float x[4];
            float s = 0.f;
#pragma unroll
            for (int ct = 0; ct < 4; ++ct) {
                x[ct] = acc[ct][e] + cv_r[ct] + h[(size_t)gr * 64 + ct * 16 + l15];
                s += x[ct];
            }
            s += __shfl_xor(s, 1); s += __shfl_xor(s, 2);
            s += __shfl_xor(s, 4); s += __shfl_xor(s, 8);
            const float mu = s * (1.0f / 64.0f);
            float v = 0.f;
#pragma unroll
            for (int ct = 0; ct < 4; ++ct) { float d = x[ct] - mu; v = fmaf(d, d, v); }
            v += __shfl_xor(v, 1); v += __shfl_xor(v, 2);
            v += __shfl_xor(v, 4); v += __shfl_xor(v, 8);
            const float rinv = rsqrtf(v * (1.0f / 64.0f) + LN_EPS);
#pragma unroll
            for (int ct = 0; ct < 4; ++ct) {
                float xn = (x[ct] - mu) * rinv;
                out[(size_t)gr * 64 + ct * 16 + l15] = fmaxf(xn * ga_r[ct] + be_r[ct], 0.0f);
            }
        }
    }
}

extern "C" void kernel_launch(void* const* d_in, const int* in_sizes, int n_in,
                              void* d_out, int out_size, void* d_ws, size_t ws_size,
                              hipStream_t stream) {
    const float* h      = (const float*)d_in[0];
    const int*   src    = (const int*)d_in[1];
    const int*   dst    = (const int*)d_in[2];
    const float* Wn     = (const float*)d_in[3];
    const float* bn     = (const float*)d_in[4];
    const float* att    = (const float*)d_in[5];
    const float* Ws     = (const float*)d_in[6];
    const float* bias   = (const float*)d_in[7];
    const float* gamma_ = (const float*)d_in[8];
    const float* beta_  = (const float*)d_in[9];
    float* out = (float*)d_out;

    char* ws = (char*)d_ws;
    size_t off = 0;
    auto alloc = [&](size_t bytes) { void* p = ws + off; off = (off + bytes + 255) & ~(size_t)255; return p; };
    __half* h16    = (__half*)alloc((size_t)N_NODES * 64 * 2);      // 6.4 MB
    f16*   aggh16  = (f16*)alloc((size_t)N_NODES * 256 * 2);        // 25.6 MB
    float* alpha_u = (float*)alloc((size_t)N_NODES * 4 * 4);
    float* alpha_v = (float*)alloc((size_t)N_NODES * 4 * 4);
    int*   rowptr  = (int*)alloc((size_t)(N_NODES + 1) * 4);
    int*   csr_src = (int*)alloc((size_t)N_EDGES * 4);              // 3.2 MB
    float* csr_w   = (float*)alloc((size_t)N_EDGES * 4 * 4);        // 12.8 MB
    int*   g       = (int*)alloc((size_t)HB * NB1P * 4);            // 2.45 MB
    int*   off1    = (int*)alloc((size_t)HB * NB1P * 4);            // 2.45 MB
    int*   tot     = (int*)alloc((size_t)NB1P * 4);
    int*   ebuf    = (int*)alloc((size_t)N_EDGES * 4);              // 3.2 MB
    f16*   Mt16    = (f16*)alloc(16384 * 2);                        // 32 KB
    float* cvec    = (float*)alloc(64 * 4);

    k_mega1<<<PRE_BLOCKS + ALPHA_BLOCKS + HB, 256, 0, stream>>>(
        h, Wn, bn, att, Ws, bias, dst, h16, alpha_u, alpha_v, Mt16, cvec, g);
    k_s1<<<98, 256, 0, stream>>>(g, off1, tot);
    k_h1scat<<<HB, 256, 0, stream>>>(src, dst, tot, off1, ebuf);
    k_h2<<<NB1, 256, 0, stream>>>(ebuf, tot, alpha_u, alpha_v, rowptr, csr_src, csr_w);
    k_agg<<<2048, 256, 0, stream>>>(rowptr, csr_src, csr_w, h16, aggh16);
    k_post_mfma<<<782, 256, 0, stream>>>(aggh16, Mt16, cvec, h, gamma_, beta_, out);
}